// Round 14
// baseline (181.607 us; speedup 1.0000x reference)
//
#include <hip/hip_runtime.h>
#include <stdint.h>

#define DEV __device__ __forceinline__

typedef __attribute__((ext_vector_type(8))) unsigned short frag8;    // 8 bf16 = 4 VGPR
typedef __attribute__((ext_vector_type(4))) float f32x4;
typedef __attribute__((ext_vector_type(8))) unsigned short ushort8;
typedef __attribute__((ext_vector_type(4))) unsigned short ushort4v;

DEV unsigned short f2bf(float f) {
  union { float f; unsigned u; } x; x.f = f;
  unsigned r = x.u + 0x7fffu + ((x.u >> 16) & 1u);   // RNE
  return (unsigned short)(r >> 16);
}
DEV float bf2f(unsigned short b) {
  union { unsigned u; float f; } x; x.u = ((unsigned)b) << 16;
  return x.f;
}

DEV void gload_lds16(const void* g, void* l) {
  __builtin_amdgcn_global_load_lds((const __attribute__((address_space(1))) void*)g,
                                   (__attribute__((address_space(3))) void*)l, 16, 0, 0);
}

DEV void mfma_bf16(f32x4& c, frag8 a, frag8 b) {
  asm("v_mfma_f32_16x16x32_bf16 %0, %1, %2, %0" : "+v"(c) : "v"(a), "v"(b));
}

// ---------------------------------------------------------------------------
// PROVEN kernel (~731 TF band): 128x128 tile, BK=64, 4 waves, SINGLE-buffer
// 32 KiB LDS, 2-barrier K-step, XOR-swizzled LDS via pre-swizzled global
// source, bijective XCD swizzle. Do not touch.
// MODE: 0 = bf16 out
//       3 = scores: e = exp(s*scale), bf16 out, rowsum atomics
//       4 = PV: f32 out = acc/rowsum[row] + biasp[gc]
//       5 = fused q'/v': bz==0 bf16 out + u2[gc] fold (bias1 = u2p partials);
//           bz==1 per-batch transposed store
// ---------------------------------------------------------------------------
template<int MODE>
__global__ __launch_bounds__(256)
void gemm_bt(const unsigned short* __restrict__ A,
             const unsigned short* __restrict__ Bm,
             const float* __restrict__ bias0, const float* __restrict__ bias1,
             float* __restrict__ rowsum,
             void* __restrict__ Cv,
             int N, int K, float scale,
             long sA, long sB, long sC,
             int nx, int ny)
{
  __shared__ unsigned short ldsA[128 * 64];
  __shared__ unsigned short ldsB[128 * 64];

  const int tid  = threadIdx.x;
  const int lane = tid & 63;
  const int wave = tid >> 6;
  const int wm   = wave >> 1;
  const int wn   = wave & 1;

  const unsigned nwg = gridDim.x;
  const unsigned orig = blockIdx.x;
  const unsigned qq = nwg >> 3, rr = nwg & 7;
  const unsigned xcd = orig & 7, jj = orig >> 3;
  const unsigned wg = (xcd < rr ? xcd * (qq + 1) : rr * (qq + 1) + (xcd - rr) * qq) + jj;
  const unsigned bx = wg % (unsigned)nx;
  const unsigned tt = wg / (unsigned)nx;
  const unsigned by = tt % (unsigned)ny;
  const unsigned bz = tt / (unsigned)ny;

  const int bm = (int)by * 128;
  const int bn = (int)bx * 128;

  A  += (size_t)bz * (size_t)sA;
  Bm += (size_t)bz * (size_t)sB;

  const int r8  = lane >> 3;
  const int l8  = lane & 7;
  const int swz = ((l8 ^ r8) << 4);
  const size_t Kb = (size_t)K * 2;

  const char* gA = (const char*)A  + (size_t)(bm + wave * 32 + r8) * Kb + swz;
  const char* gB = (const char*)Bm + (size_t)(bn + wave * 32 + r8) * Kb + swz;
  char* lA = (char*)ldsA + wave * 32 * 128;
  char* lB = (char*)ldsB + wave * 32 * 128;

  const int cr = lane & 15;
  const int kq = lane >> 4;
  const int base16 = ((kq ^ (cr & 7)) << 4);
  const char* rowA = (const char*)ldsA + (wm * 64 + cr) * 128;
  const char* rowB = (const char*)ldsB + (wn * 64 + cr) * 128;

  f32x4 acc[4][4];
  #pragma unroll
  for (int m = 0; m < 4; ++m)
    #pragma unroll
    for (int n = 0; n < 4; ++n)
      acc[m][n] = f32x4{0.f, 0.f, 0.f, 0.f};

  const int nk = K >> 6;
  for (int kt = 0; kt < nk; ++kt) {
    __syncthreads();
    {
      const char* ga = gA + (size_t)kt * 128;
      const char* gb = gB + (size_t)kt * 128;
      gload_lds16(ga,           lA);
      gload_lds16(gb,           lB);
      gload_lds16(ga +  8 * Kb, lA + 1024);
      gload_lds16(gb +  8 * Kb, lB + 1024);
      gload_lds16(ga + 16 * Kb, lA + 2048);
      gload_lds16(gb + 16 * Kb, lB + 2048);
      gload_lds16(ga + 24 * Kb, lA + 3072);
      gload_lds16(gb + 24 * Kb, lB + 3072);
    }
    __syncthreads();
    #pragma unroll
    for (int kk = 0; kk < 2; ++kk) {
      const int off = base16 ^ (kk << 6);
      frag8 a[4], b[4];
      #pragma unroll
      for (int f = 0; f < 4; ++f) {
        a[f] = *(const frag8*)(rowA + f * 2048 + off);
        b[f] = *(const frag8*)(rowB + f * 2048 + off);
      }
      #pragma unroll
      for (int m = 0; m < 4; ++m)
        #pragma unroll
        for (int n = 0; n < 4; ++n)
          mfma_bf16(acc[m][n], a[m], b[n]);
    }
  }

  #pragma unroll
  for (int m = 0; m < 4; ++m) {
    const int gr0 = bm + wm * 64 + m * 16 + kq * 4;
    float psum[4] = {0.f, 0.f, 0.f, 0.f};
    float inv0 = 1.f, inv1 = 1.f, inv2 = 1.f, inv3 = 1.f;
    if constexpr (MODE == 4) {
      const float4 rs = *(const float4*)&bias0[(size_t)bz * 2048 + gr0];
      inv0 = 1.f / rs.x; inv1 = 1.f / rs.y; inv2 = 1.f / rs.z; inv3 = 1.f / rs.w;
    }
    #pragma unroll
    for (int n = 0; n < 4; ++n) {
      const int gc = bn + wn * 64 + n * 16 + cr;
      float v0 = acc[m][n][0], v1 = acc[m][n][1], v2 = acc[m][n][2], v3 = acc[m][n][3];
      if constexpr (MODE == 3) {
        unsigned short* C = (unsigned short*)Cv + (size_t)bz * (size_t)sC;
        unsigned short e0 = f2bf(__expf(v0 * scale));
        unsigned short e1 = f2bf(__expf(v1 * scale));
        unsigned short e2 = f2bf(__expf(v2 * scale));
        unsigned short e3 = f2bf(__expf(v3 * scale));
        C[(size_t)(gr0 + 0) * N + gc] = e0;
        C[(size_t)(gr0 + 1) * N + gc] = e1;
        C[(size_t)(gr0 + 2) * N + gc] = e2;
        C[(size_t)(gr0 + 3) * N + gc] = e3;
        psum[0] += bf2f(e0); psum[1] += bf2f(e1);
        psum[2] += bf2f(e2); psum[3] += bf2f(e3);
      } else if constexpr (MODE == 4) {
        const float bb = bias1[gc];
        float* C = (float*)Cv + (size_t)bz * (size_t)sC;
        C[(size_t)(gr0 + 0) * N + gc] = v0 * inv0 + bb;
        C[(size_t)(gr0 + 1) * N + gc] = v1 * inv1 + bb;
        C[(size_t)(gr0 + 2) * N + gc] = v2 * inv2 + bb;
        C[(size_t)(gr0 + 3) * N + gc] = v3 * inv3 + bb;
      } else if constexpr (MODE == 5) {
        if (bz == 1) {
          // transposed store: v'T[b][d][s], b = gr0>>11, s = gr0&2047, d = gc
          unsigned short* C = (unsigned short*)Cv + (size_t)sC;
          ushort4v u;
          u[0] = f2bf(v0); u[1] = f2bf(v1); u[2] = f2bf(v2); u[3] = f2bf(v3);
          *(ushort4v*)&C[((size_t)(gr0 >> 11) << 21) + (size_t)gc * 2048 + (gr0 & 2047)] = u;
        } else {
          // q' row: fold u2[gc] = sum of 4 u2p partials (scores = (QT+1*u2)K^T)
          const float u2v = bias1[gc] + bias1[1024 + gc]
                          + bias1[2048 + gc] + bias1[3072 + gc];
          unsigned short* C = (unsigned short*)Cv;
          C[(size_t)(gr0 + 0) * N + gc] = f2bf(v0 + u2v);
          C[(size_t)(gr0 + 1) * N + gc] = f2bf(v1 + u2v);
          C[(size_t)(gr0 + 2) * N + gc] = f2bf(v2 + u2v);
          C[(size_t)(gr0 + 3) * N + gc] = f2bf(v3 + u2v);
        }
      } else {
        unsigned short* C = (unsigned short*)Cv + (size_t)bz * (size_t)sC;
        C[(size_t)(gr0 + 0) * N + gc] = f2bf(v0);
        C[(size_t)(gr0 + 1) * N + gc] = f2bf(v1);
        C[(size_t)(gr0 + 2) * N + gc] = f2bf(v2);
        C[(size_t)(gr0 + 3) * N + gc] = f2bf(v3);
      }
    }
    if constexpr (MODE == 3) {
      #pragma unroll
      for (int j = 0; j < 4; ++j) {
        float p = psum[j];
        p += __shfl_xor(p, 1);
        p += __shfl_xor(p, 2);
        p += __shfl_xor(p, 4);
        p += __shfl_xor(p, 8);
        if (cr == 0) atomicAdd(&rowsum[(size_t)bz * 2048 + gr0 + j], p);
      }
    }
  }
}

// ---------------------------------------------------------------------------
// front (r13 + deep-MLP converts): ALL independent prep in one dispatch.
//  [0,768)      : transpose WQ/WK/WV f32 -> bf16 (WQt/WKt/WVt)
//  [768,1792)   : Weff row + fused biasp
//  [1792,1808)  : u2 partials u2p[mc][k] (no atomics)
//  [1808,1812)  : zero rowsum[8192]
//  [1812,3348)  : cvt Q/V/K f32 -> bf16; 512 blocks/tensor, 8 slots/thread,
//                 ALL 16 float4 loads issued before any cvt/store (256 B
//                 in flight per thread — MLP fix for the 2.1 TB/s plateau)
// ---------------------------------------------------------------------------
__global__ __launch_bounds__(256)
void front_kernel(const float* __restrict__ WQ, const float* __restrict__ WK,
                  const float* __restrict__ WV, const float* __restrict__ Wl,
                  const float* __restrict__ Qf, const float* __restrict__ Vf,
                  const float* __restrict__ Kf,
                  const float* __restrict__ bQ, const float* __restrict__ bV,
                  const float* __restrict__ bl,
                  unsigned short* __restrict__ Wr,
                  unsigned short* __restrict__ Xb,
                  float* __restrict__ u2p, float* __restrict__ biasp,
                  float* __restrict__ rowsum)
{
  __shared__ float t[64][65];
  const int blk = blockIdx.x;
  const int tid = threadIdx.x;

  if (blk < 768) {
    const int z = blk >> 8;
    const int local = blk & 255;
    const float* src = (z == 0) ? WQ : (z == 1) ? WK : WV;
    unsigned short* dst = Wr + (size_t)((z == 0) ? 2 : (z == 1) ? 0 : 3) * 1024 * 1024;
    const int bx  = local & 15;
    const int byy = local >> 4;
    const int tx  = tid & 63;
    const int ty4 = tid >> 6;
    #pragma unroll
    for (int i = 0; i < 16; ++i) {
      const int r = i * 4 + ty4;
      t[r][tx] = src[(size_t)(byy * 64 + r) * 1024 + bx * 64 + tx];
    }
    __syncthreads();
    #pragma unroll
    for (int i = 0; i < 16; ++i) {
      const int r = i * 4 + ty4;
      dst[(size_t)(bx * 64 + r) * 1024 + byy * 64 + tx] = f2bf(t[tx][r]);
    }
  } else if (blk < 1792) {
    const int j = blk - 768;
    const int d = tid * 4;
    float4 s = make_float4(0.f, 0.f, 0.f, 0.f);
    #pragma unroll
    for (int h = 0; h < 8; ++h) {
      float4 w = *(const float4*)&Wl[(size_t)j * 8192 + h * 1024 + d];
      s.x += w.x; s.y += w.y; s.z += w.z; s.w += w.w;
    }
    unsigned short* Weffb = Wr + (size_t)1024 * 1024;
    ushort4v o;
    o[0] = f2bf(s.x); o[1] = f2bf(s.y); o[2] = f2bf(s.z); o[3] = f2bf(s.w);
    *(ushort4v*)&Weffb[(size_t)j * 1024 + d] = o;
    const float4 bv = *(const float4*)&bV[d];
    float p = s.x * bv.x + s.y * bv.y + s.z * bv.z + s.w * bv.w;
    #pragma unroll
    for (int off = 32; off; off >>= 1) p += __shfl_xor(p, off);
    __shared__ float red[4];
    if ((tid & 63) == 0) red[tid >> 6] = p;
    __syncthreads();
    if (tid == 0) biasp[j] = red[0] + red[1] + red[2] + red[3] + bl[j];
  } else if (blk < 1808) {
    const int idx = blk - 1792;
    const int kc = idx & 3, mc = idx >> 2;
    const int k = kc * 256 + tid;
    const int m0 = mc * 256;
    float a = 0.f;
    for (int m = m0; m < m0 + 256; ++m)
      a += WK[(size_t)m * 1024 + k] * bQ[m];
    u2p[(size_t)mc * 1024 + k] = a;
  } else if (blk < 1812) {
    const int i = (blk - 1808) * 2048 + tid * 8;
    #pragma unroll
    for (int j = 0; j < 8; ++j) rowsum[i + j] = 0.f;
  } else {
    const int local = blk - 1812;             // 0..1535
    const int z = local >> 9;                 // 0:Q 1:V 2:K
    const float* src = (z == 0) ? Qf : (z == 1) ? Vf : Kf;
    unsigned short* dst = Xb + (size_t)z * (size_t)8192 * 1024;
    const int t0 = (local & 511) * 256 + tid; // ushort8-group slot, [0,131072)
    const int stride = 512 * 256;             // 131072 groups per step
    float4 a[8], b[8];
    #pragma unroll
    for (int j = 0; j < 8; ++j) {             // issue all 16 loads first
      const float4* p = (const float4*)src + (size_t)(t0 + j * stride) * 2;
      a[j] = p[0];
      b[j] = p[1];
    }
    #pragma unroll
    for (int j = 0; j < 8; ++j) {
      ushort8 o;
      o[0] = f2bf(a[j].x); o[1] = f2bf(a[j].y);
      o[2] = f2bf(a[j].z); o[3] = f2bf(a[j].w);
      o[4] = f2bf(b[j].x); o[5] = f2bf(b[j].y);
      o[6] = f2bf(b[j].z); o[7] = f2bf(b[j].w);
      *((ushort8*)dst + (size_t)(t0 + j * stride)) = o;
    }
  }
}

// ---------------------------------------------------------------------------
extern "C" void kernel_launch(void* const* d_in, const int* in_sizes, int n_in,
                              void* d_out, int out_size, void* d_ws, size_t ws_size,
                              hipStream_t stream)
{
  (void)in_sizes; (void)n_in; (void)out_size; (void)ws_size;

  const float* Q  = (const float*)d_in[0];
  const float* K  = (const float*)d_in[1];
  const float* V  = (const float*)d_in[2];
  const float* WQ = (const float*)d_in[3];
  const float* bQ = (const float*)d_in[4];
  const float* WK = (const float*)d_in[5];
  const float* bK = (const float*)d_in[6];  (void)bK;  // cancels in softmax
  const float* WV = (const float*)d_in[7];
  const float* bV = (const float*)d_in[8];
  const float* Wl = (const float*)d_in[9];
  const float* bl = (const float*)d_in[10];

  const size_t nX = (size_t)8192 * 1024;   // B*S*D
  const size_t nW = (size_t)1024 * 1024;

  // workspace (bf16 elements):
  // [Qb][Vb][Kb][q'][v'T] | weights: [WKt][Weffb][WQt][WVt][Tt][Wve] | f32 vecs
  // P ([4][2048][2048] = 2*nX) overlays Qb+Vb after they are consumed.
  unsigned short* Qb  = (unsigned short*)d_ws;
  unsigned short* Kb  = Qb + 2 * nX;
  unsigned short* qp  = Qb + 3 * nX;       // q' [8192][1024]; v'T at +nX
  unsigned short* Wr  = Qb + 5 * nX;       // weight region base (= WKt)
  unsigned short* WQt = Wr + 2 * nW;
  unsigned short* Tt  = Wr + 4 * nW;
  float* Fv    = (float*)(Wr + 6 * nW);
  float* rowsum = Fv;                      // 8192
  float* u2p    = Fv + 8192;               // 4 x 1024 partials
  float* biasp  = Fv + 20480;              // 1024
  unsigned short* Pb = Qb;                 // overlays [0, 2*nX)

  const int thr = 256;

  // 1) all independent prep + Q/V/K converts, one dispatch
  front_kernel<<<3348, thr, 0, stream>>>(WQ, WK, WV, Wl, Q, V, K, bQ, bV, bl,
                                         Wr, Qb, u2p, biasp, rowsum);
  // 2) Tt = WKt @ WQt^T (bz=0), Wve = Weff @ WVt^T (bz=1)
  gemm_bt<0><<<128, thr, 0, stream>>>(
      Wr, WQt, nullptr, nullptr, nullptr, Tt, 1024, 1024, 1.f,
      (long)nW, (long)nW, (long)nW, 8, 8);
  // 3) q' = Qb @ Tt^T + u2 (bz=0), v'T = (Vb @ Wve^T)^T (bz=1)
  gemm_bt<5><<<1024, thr, 0, stream>>>(
      Qb, Tt, nullptr, u2p, nullptr, qp, 1024, 1024, 1.f,
      (long)nX, (long)nW, (long)nX, 8, 64);
  // 4) P = exp(q'' K^T / 32), rowsum accumulated
  gemm_bt<3><<<1024, thr, 0, stream>>>(
      qp, Kb, nullptr, nullptr, rowsum, Pb, 2048, 1024, 0.03125f,
      (long)(2048 * 1024), (long)(2048 * 1024), (long)(2048 * 2048), 16, 16);
  // 5) out = (P @ v'T^T)/rowsum + biasp -> f32
  gemm_bt<4><<<512, thr, 0, stream>>>(
      Pb, qp + nX, rowsum, biasp, nullptr, d_out, 1024, 2048, 1.f,
      (long)(2048 * 2048), (long)(1024 * 2048), (long)(2048 * 1024), 8, 16);
}

// Round 15
// 180.010 us; speedup vs baseline: 1.0089x; 1.0089x over previous
//
#include <hip/hip_runtime.h>
#include <stdint.h>

#define DEV __device__ __forceinline__

typedef __attribute__((ext_vector_type(8))) unsigned short frag8;    // 8 bf16 = 4 VGPR
typedef __attribute__((ext_vector_type(4))) float f32x4;
typedef __attribute__((ext_vector_type(8))) unsigned short ushort8;
typedef __attribute__((ext_vector_type(4))) unsigned short ushort4v;

DEV unsigned short f2bf(float f) {
  union { float f; unsigned u; } x; x.f = f;
  unsigned r = x.u + 0x7fffu + ((x.u >> 16) & 1u);   // RNE
  return (unsigned short)(r >> 16);
}
DEV float bf2f(unsigned short b) {
  union { unsigned u; float f; } x; x.u = ((unsigned)b) << 16;
  return x.f;
}

DEV void gload_lds16(const void* g, void* l) {
  __builtin_amdgcn_global_load_lds((const __attribute__((address_space(1))) void*)g,
                                   (__attribute__((address_space(3))) void*)l, 16, 0, 0);
}

DEV void mfma_bf16(f32x4& c, frag8 a, frag8 b) {
  asm("v_mfma_f32_16x16x32_bf16 %0, %1, %2, %0" : "+v"(c) : "v"(a), "v"(b));
}

// ---------------------------------------------------------------------------
// PROVEN kernel (~731 TF band): 128x128 tile, BK=64, 4 waves, SINGLE-buffer
// 32 KiB LDS, 2-barrier K-step, XOR-swizzled LDS via pre-swizzled global
// source, bijective XCD swizzle. Do not touch.
// MODE: 0 = bf16 out
//       3 = scores: e = exp(s*scale), bf16 out, rowsum atomics
//       4 = PV: f32 out = acc/rowsum[row] + biasp[gc]
//       5 = fused q'/v': bz==0 bf16 out + u2[gc] fold (bias1 = u2p partials);
//           bz==1 per-batch transposed store
// ---------------------------------------------------------------------------
template<int MODE>
__global__ __launch_bounds__(256)
void gemm_bt(const unsigned short* __restrict__ A,
             const unsigned short* __restrict__ Bm,
             const float* __restrict__ bias0, const float* __restrict__ bias1,
             float* __restrict__ rowsum,
             void* __restrict__ Cv,
             int N, int K, float scale,
             long sA, long sB, long sC,
             int nx, int ny)
{
  __shared__ unsigned short ldsA[128 * 64];
  __shared__ unsigned short ldsB[128 * 64];

  const int tid  = threadIdx.x;
  const int lane = tid & 63;
  const int wave = tid >> 6;
  const int wm   = wave >> 1;
  const int wn   = wave & 1;

  const unsigned nwg = gridDim.x;
  const unsigned orig = blockIdx.x;
  const unsigned qq = nwg >> 3, rr = nwg & 7;
  const unsigned xcd = orig & 7, jj = orig >> 3;
  const unsigned wg = (xcd < rr ? xcd * (qq + 1) : rr * (qq + 1) + (xcd - rr) * qq) + jj;
  const unsigned bx = wg % (unsigned)nx;
  const unsigned tt = wg / (unsigned)nx;
  const unsigned by = tt % (unsigned)ny;
  const unsigned bz = tt / (unsigned)ny;

  const int bm = (int)by * 128;
  const int bn = (int)bx * 128;

  A  += (size_t)bz * (size_t)sA;
  Bm += (size_t)bz * (size_t)sB;

  const int r8  = lane >> 3;
  const int l8  = lane & 7;
  const int swz = ((l8 ^ r8) << 4);
  const size_t Kb = (size_t)K * 2;

  const char* gA = (const char*)A  + (size_t)(bm + wave * 32 + r8) * Kb + swz;
  const char* gB = (const char*)Bm + (size_t)(bn + wave * 32 + r8) * Kb + swz;
  char* lA = (char*)ldsA + wave * 32 * 128;
  char* lB = (char*)ldsB + wave * 32 * 128;

  const int cr = lane & 15;
  const int kq = lane >> 4;
  const int base16 = ((kq ^ (cr & 7)) << 4);
  const char* rowA = (const char*)ldsA + (wm * 64 + cr) * 128;
  const char* rowB = (const char*)ldsB + (wn * 64 + cr) * 128;

  f32x4 acc[4][4];
  #pragma unroll
  for (int m = 0; m < 4; ++m)
    #pragma unroll
    for (int n = 0; n < 4; ++n)
      acc[m][n] = f32x4{0.f, 0.f, 0.f, 0.f};

  const int nk = K >> 6;
  for (int kt = 0; kt < nk; ++kt) {
    __syncthreads();
    {
      const char* ga = gA + (size_t)kt * 128;
      const char* gb = gB + (size_t)kt * 128;
      gload_lds16(ga,           lA);
      gload_lds16(gb,           lB);
      gload_lds16(ga +  8 * Kb, lA + 1024);
      gload_lds16(gb +  8 * Kb, lB + 1024);
      gload_lds16(ga + 16 * Kb, lA + 2048);
      gload_lds16(gb + 16 * Kb, lB + 2048);
      gload_lds16(ga + 24 * Kb, lA + 3072);
      gload_lds16(gb + 24 * Kb, lB + 3072);
    }
    __syncthreads();
    #pragma unroll
    for (int kk = 0; kk < 2; ++kk) {
      const int off = base16 ^ (kk << 6);
      frag8 a[4], b[4];
      #pragma unroll
      for (int f = 0; f < 4; ++f) {
        a[f] = *(const frag8*)(rowA + f * 2048 + off);
        b[f] = *(const frag8*)(rowB + f * 2048 + off);
      }
      #pragma unroll
      for (int m = 0; m < 4; ++m)
        #pragma unroll
        for (int n = 0; n < 4; ++n)
          mfma_bf16(acc[m][n], a[m], b[n]);
    }
  }

  #pragma unroll
  for (int m = 0; m < 4; ++m) {
    const int gr0 = bm + wm * 64 + m * 16 + kq * 4;
    float psum[4] = {0.f, 0.f, 0.f, 0.f};
    float inv0 = 1.f, inv1 = 1.f, inv2 = 1.f, inv3 = 1.f;
    if constexpr (MODE == 4) {
      const float4 rs = *(const float4*)&bias0[(size_t)bz * 2048 + gr0];
      inv0 = 1.f / rs.x; inv1 = 1.f / rs.y; inv2 = 1.f / rs.z; inv3 = 1.f / rs.w;
    }
    #pragma unroll
    for (int n = 0; n < 4; ++n) {
      const int gc = bn + wn * 64 + n * 16 + cr;
      float v0 = acc[m][n][0], v1 = acc[m][n][1], v2 = acc[m][n][2], v3 = acc[m][n][3];
      if constexpr (MODE == 3) {
        unsigned short* C = (unsigned short*)Cv + (size_t)bz * (size_t)sC;
        unsigned short e0 = f2bf(__expf(v0 * scale));
        unsigned short e1 = f2bf(__expf(v1 * scale));
        unsigned short e2 = f2bf(__expf(v2 * scale));
        unsigned short e3 = f2bf(__expf(v3 * scale));
        C[(size_t)(gr0 + 0) * N + gc] = e0;
        C[(size_t)(gr0 + 1) * N + gc] = e1;
        C[(size_t)(gr0 + 2) * N + gc] = e2;
        C[(size_t)(gr0 + 3) * N + gc] = e3;
        psum[0] += bf2f(e0); psum[1] += bf2f(e1);
        psum[2] += bf2f(e2); psum[3] += bf2f(e3);
      } else if constexpr (MODE == 4) {
        const float bb = bias1[gc];
        float* C = (float*)Cv + (size_t)bz * (size_t)sC;
        C[(size_t)(gr0 + 0) * N + gc] = v0 * inv0 + bb;
        C[(size_t)(gr0 + 1) * N + gc] = v1 * inv1 + bb;
        C[(size_t)(gr0 + 2) * N + gc] = v2 * inv2 + bb;
        C[(size_t)(gr0 + 3) * N + gc] = v3 * inv3 + bb;
      } else if constexpr (MODE == 5) {
        if (bz == 1) {
          // transposed store: v'T[b][d][s], b = gr0>>11, s = gr0&2047, d = gc
          unsigned short* C = (unsigned short*)Cv + (size_t)sC;
          ushort4v u;
          u[0] = f2bf(v0); u[1] = f2bf(v1); u[2] = f2bf(v2); u[3] = f2bf(v3);
          *(ushort4v*)&C[((size_t)(gr0 >> 11) << 21) + (size_t)gc * 2048 + (gr0 & 2047)] = u;
        } else {
          // q' row: fold u2[gc] = sum of 4 u2p partials (scores = (QT+1*u2)K^T)
          const float u2v = bias1[gc] + bias1[1024 + gc]
                          + bias1[2048 + gc] + bias1[3072 + gc];
          unsigned short* C = (unsigned short*)Cv;
          C[(size_t)(gr0 + 0) * N + gc] = f2bf(v0 + u2v);
          C[(size_t)(gr0 + 1) * N + gc] = f2bf(v1 + u2v);
          C[(size_t)(gr0 + 2) * N + gc] = f2bf(v2 + u2v);
          C[(size_t)(gr0 + 3) * N + gc] = f2bf(v3 + u2v);
        }
      } else {
        unsigned short* C = (unsigned short*)Cv + (size_t)bz * (size_t)sC;
        C[(size_t)(gr0 + 0) * N + gc] = f2bf(v0);
        C[(size_t)(gr0 + 1) * N + gc] = f2bf(v1);
        C[(size_t)(gr0 + 2) * N + gc] = f2bf(v2);
        C[(size_t)(gr0 + 3) * N + gc] = f2bf(v3);
      }
    }
    if constexpr (MODE == 3) {
      #pragma unroll
      for (int j = 0; j < 4; ++j) {
        float p = psum[j];
        p += __shfl_xor(p, 1);
        p += __shfl_xor(p, 2);
        p += __shfl_xor(p, 4);
        p += __shfl_xor(p, 8);
        if (cr == 0) atomicAdd(&rowsum[(size_t)bz * 2048 + gr0 + j], p);
      }
    }
  }
}

// ---------------------------------------------------------------------------
// front (r13/r9 proven): ALL independent prep in one dispatch.
//  [0,768)      : transpose WQ/WK/WV f32 -> bf16 (WQt/WKt/WVt)
//  [768,1792)   : Weff row + fused biasp
//  [1792,1808)  : u2 partials u2p[mc][k] (no atomics)
//  [1808,1812)  : zero rowsum[8192]
//  [1812,3348)  : cvt Q/V/K f32 -> bf16 (512 grid-stride blocks per tensor)
// ---------------------------------------------------------------------------
__global__ __launch_bounds__(256)
void front_kernel(const float* __restrict__ WQ, const float* __restrict__ WK,
                  const float* __restrict__ WV, const float* __restrict__ Wl,
                  const float* __restrict__ Qf, const float* __restrict__ Vf,
                  const float* __restrict__ Kf,
                  const float* __restrict__ bQ, const float* __restrict__ bV,
                  const float* __restrict__ bl,
                  unsigned short* __restrict__ Wr,
                  unsigned short* __restrict__ Xb,
                  float* __restrict__ u2p, float* __restrict__ biasp,
                  float* __restrict__ rowsum)
{
  __shared__ float t[64][65];
  const int blk = blockIdx.x;
  const int tid = threadIdx.x;

  if (blk < 768) {
    const int z = blk >> 8;
    const int local = blk & 255;
    const float* src = (z == 0) ? WQ : (z == 1) ? WK : WV;
    unsigned short* dst = Wr + (size_t)((z == 0) ? 2 : (z == 1) ? 0 : 3) * 1024 * 1024;
    const int bx  = local & 15;
    const int byy = local >> 4;
    const int tx  = tid & 63;
    const int ty4 = tid >> 6;
    #pragma unroll
    for (int i = 0; i < 16; ++i) {
      const int r = i * 4 + ty4;
      t[r][tx] = src[(size_t)(byy * 64 + r) * 1024 + bx * 64 + tx];
    }
    __syncthreads();
    #pragma unroll
    for (int i = 0; i < 16; ++i) {
      const int r = i * 4 + ty4;
      dst[(size_t)(bx * 64 + r) * 1024 + byy * 64 + tx] = f2bf(t[tx][r]);
    }
  } else if (blk < 1792) {
    const int j = blk - 768;
    const int d = tid * 4;
    float4 s = make_float4(0.f, 0.f, 0.f, 0.f);
    #pragma unroll
    for (int h = 0; h < 8; ++h) {
      float4 w = *(const float4*)&Wl[(size_t)j * 8192 + h * 1024 + d];
      s.x += w.x; s.y += w.y; s.z += w.z; s.w += w.w;
    }
    unsigned short* Weffb = Wr + (size_t)1024 * 1024;
    ushort4v o;
    o[0] = f2bf(s.x); o[1] = f2bf(s.y); o[2] = f2bf(s.z); o[3] = f2bf(s.w);
    *(ushort4v*)&Weffb[(size_t)j * 1024 + d] = o;
    const float4 bv = *(const float4*)&bV[d];
    float p = s.x * bv.x + s.y * bv.y + s.z * bv.z + s.w * bv.w;
    #pragma unroll
    for (int off = 32; off; off >>= 1) p += __shfl_xor(p, off);
    __shared__ float red[4];
    if ((tid & 63) == 0) red[tid >> 6] = p;
    __syncthreads();
    if (tid == 0) biasp[j] = red[0] + red[1] + red[2] + red[3] + bl[j];
  } else if (blk < 1808) {
    const int idx = blk - 1792;
    const int kc = idx & 3, mc = idx >> 2;
    const int k = kc * 256 + tid;
    const int m0 = mc * 256;
    float a = 0.f;
    for (int m = m0; m < m0 + 256; ++m)
      a += WK[(size_t)m * 1024 + k] * bQ[m];
    u2p[(size_t)mc * 1024 + k] = a;
  } else if (blk < 1812) {
    const int i = (blk - 1808) * 2048 + tid * 8;
    #pragma unroll
    for (int j = 0; j < 8; ++j) rowsum[i + j] = 0.f;
  } else {
    const int local = blk - 1812;             // 0..1535
    const int z = local >> 9;                 // 0:Q 1:V 2:K
    const float* src = (z == 0) ? Qf : (z == 1) ? Vf : Kf;
    unsigned short* dst = Xb + (size_t)z * (size_t)8192 * 1024;
    int i = (local & 511) * 256 + tid;
    const int n8 = 1048576;                   // 8192*1024/8
    for (; i < n8; i += 512 * 256) {
      const float4* p = (const float4*)src + (size_t)i * 2;
      float4 a = p[0], b = p[1];
      ushort8 o;
      o[0] = f2bf(a.x); o[1] = f2bf(a.y); o[2] = f2bf(a.z); o[3] = f2bf(a.w);
      o[4] = f2bf(b.x); o[5] = f2bf(b.y); o[6] = f2bf(b.z); o[7] = f2bf(b.w);
      *((ushort8*)dst + i) = o;
    }
  }
}

// ---------------------------------------------------------------------------
extern "C" void kernel_launch(void* const* d_in, const int* in_sizes, int n_in,
                              void* d_out, int out_size, void* d_ws, size_t ws_size,
                              hipStream_t stream)
{
  (void)in_sizes; (void)n_in; (void)out_size; (void)ws_size;

  const float* Q  = (const float*)d_in[0];
  const float* K  = (const float*)d_in[1];
  const float* V  = (const float*)d_in[2];
  const float* WQ = (const float*)d_in[3];
  const float* bQ = (const float*)d_in[4];
  const float* WK = (const float*)d_in[5];
  const float* bK = (const float*)d_in[6];  (void)bK;  // cancels in softmax
  const float* WV = (const float*)d_in[7];
  const float* bV = (const float*)d_in[8];
  const float* Wl = (const float*)d_in[9];
  const float* bl = (const float*)d_in[10];

  const size_t nX = (size_t)8192 * 1024;   // B*S*D
  const size_t nW = (size_t)1024 * 1024;

  // workspace (bf16 elements):
  // [Qb][Vb][Kb][q'][v'T] | weights: [WKt][Weffb][WQt][WVt][Tt][Wve] | f32 vecs
  // P ([4][2048][2048] = 2*nX) overlays Qb+Vb after they are consumed.
  unsigned short* Qb  = (unsigned short*)d_ws;
  unsigned short* Kb  = Qb + 2 * nX;
  unsigned short* qp  = Qb + 3 * nX;       // q' [8192][1024]; v'T at +nX
  unsigned short* Wr  = Qb + 5 * nX;       // weight region base (= WKt)
  unsigned short* WQt = Wr + 2 * nW;
  unsigned short* Tt  = Wr + 4 * nW;
  float* Fv    = (float*)(Wr + 6 * nW);
  float* rowsum = Fv;                      // 8192
  float* u2p    = Fv + 8192;               // 4 x 1024 partials
  float* biasp  = Fv + 20480;              // 1024
  unsigned short* Pb = Qb;                 // overlays [0, 2*nX)

  const int thr = 256;

  // 1) all independent prep + Q/V/K converts, one dispatch (r13 proven best)
  front_kernel<<<3348, thr, 0, stream>>>(WQ, WK, WV, Wl, Q, V, K, bQ, bV, bl,
                                         Wr, Qb, u2p, biasp, rowsum);
  // 2) Tt = WKt @ WQt^T (bz=0), Wve = Weff @ WVt^T (bz=1)
  gemm_bt<0><<<128, thr, 0, stream>>>(
      Wr, WQt, nullptr, nullptr, nullptr, Tt, 1024, 1024, 1.f,
      (long)nW, (long)nW, (long)nW, 8, 8);
  // 3) q' = Qb @ Tt^T + u2 (bz=0), v'T = (Vb @ Wve^T)^T (bz=1)
  gemm_bt<5><<<1024, thr, 0, stream>>>(
      Qb, Tt, nullptr, u2p, nullptr, qp, 1024, 1024, 1.f,
      (long)nX, (long)nW, (long)nX, 8, 64);
  // 4) P = exp(q'' K^T / 32), rowsum accumulated
  gemm_bt<3><<<1024, thr, 0, stream>>>(
      qp, Kb, nullptr, nullptr, rowsum, Pb, 2048, 1024, 0.03125f,
      (long)(2048 * 1024), (long)(2048 * 1024), (long)(2048 * 2048), 16, 16);
  // 5) out = (P @ v'T^T)/rowsum + biasp -> f32
  gemm_bt<4><<<512, thr, 0, stream>>>(
      Pb, qp + nX, rowsum, biasp, nullptr, d_out, 1024, 2048, 1.f,
      (long)(2048 * 2048), (long)(1024 * 2048), (long)(2048 * 1024), 8, 16);
}